// Round 2
// baseline (60.188 us; speedup 1.0000x reference)
//
#include <hip/hip_runtime.h>

// similarity[r] = sum_a (pp[r,a] - ph[a])^2, a in [0,32); output = min_r similarity[r]
// pp: [R, 32] fp32 row-major, ph: [32] fp32, out: 1 fp32 scalar.
//
// Structure: one row per lane. Each lane issues 8 independent float4 loads
// (its own 128 B row), computes the squared distance lane-locally, and keeps
// a per-lane running min. No DS ops in the hot path; the wave/block min
// reduction runs once per thread lifetime. Phases are wave-uniform -> SGPRs.

__global__ void doa_init_out(unsigned int* out) {
    // +inf bits; fp32 sums of squares are >= 0, so uint ordering == float ordering
    *out = 0x7F800000u;
}

__global__ __launch_bounds__(256) void doa_min_kernel(
    const float* __restrict__ pp,
    const float* __restrict__ ph,
    unsigned int* __restrict__ out,
    int R)
{
    const int r = blockIdx.x * 256 + threadIdx.x;

    // phases: lane-uniform loads -> compiler scalarizes to SGPRs (s_load_dwordx16)
    float q[32];
#pragma unroll
    for (int a = 0; a < 32; ++a) q[a] = ph[a];

    float s = __builtin_inff();
    if (r < R) {
        const float4* row = reinterpret_cast<const float4*>(pp) + (size_t)r * 8;
        // 8 independent loads issued back-to-back: full-row MLP, no shuffle
        // between load and use, all 64B lines fully consumed within the wave's
        // k=0..7 slices (L1 reuse).
        float4 v[8];
#pragma unroll
        for (int k = 0; k < 8; ++k) v[k] = row[k];

        s = 0.0f;
#pragma unroll
        for (int k = 0; k < 8; ++k) {
            const float dx = v[k].x - q[4 * k + 0];
            const float dy = v[k].y - q[4 * k + 1];
            const float dz = v[k].z - q[4 * k + 2];
            const float dw = v[k].w - q[4 * k + 3];
            s += dx * dx + dy * dy + dz * dz + dw * dw;
        }
    }

    // one wave-wide min butterfly per wave (not per row)
#pragma unroll
    for (int off = 1; off < 64; off <<= 1)
        s = fminf(s, __shfl_xor(s, off));

    __shared__ float wmin[4];
    const int lane = threadIdx.x & 63;
    const int wid  = threadIdx.x >> 6;
    if (lane == 0) wmin[wid] = s;
    __syncthreads();
    if (threadIdx.x == 0) {
        const float m = fminf(fminf(wmin[0], wmin[1]), fminf(wmin[2], wmin[3]));
        atomicMin(out, __float_as_uint(m));
    }
}

extern "C" void kernel_launch(void* const* d_in, const int* in_sizes, int n_in,
                              void* d_out, int out_size, void* d_ws, size_t ws_size,
                              hipStream_t stream) {
    const float* pp = (const float*)d_in[0];   // possible_phases [R, 32]
    const float* ph = (const float*)d_in[1];   // phases [32]
    unsigned int* out = (unsigned int*)d_out;  // 1 fp32 scalar

    const int R = in_sizes[0] / 32;

    doa_init_out<<<1, 1, 0, stream>>>(out);

    const int block = 256;
    const int grid = (R + block - 1) / block;  // one row per thread
    doa_min_kernel<<<grid, block, 0, stream>>>(pp, ph, out, R);
}